// Round 1
// baseline (411.445 us; speedup 1.0000x reference)
//
#include <hip/hip_runtime.h>

#define TAGS 64
#define START_TAG 62
#define STOP_TAG 63
#define BATCH 512
#define SLEN 1024
#define HALF 512

__device__ __forceinline__ float rl(float v, int l) {
  return __int_as_float(__builtin_amdgcn_readlane(__float_as_int(v), l));
}
__device__ __forceinline__ float rfl(float v) {
  return __int_as_float(__builtin_amdgcn_readfirstlane(__float_as_int(v)));
}

// Blocks 0..511: one batch each, wave0 = forward half, wave1 = backward half.
// Blocks 512..1023: gold score for batch (blk-512).
__global__ __launch_bounds__(128, 1)
void crf_main(const float* __restrict__ feats, const float* __restrict__ trans,
              const int* __restrict__ tags, const int* __restrict__ mask,
              float* __restrict__ ws) {
  __shared__ float shf[260];
  const int blk = blockIdx.x;
  const int lane = threadIdx.x & 63;
  const int wave = threadIdx.x >> 6;

  if (blk < BATCH) {
    const int b = blk;
    const float* fb = feats + (size_t)b * SLEN * TAGS;
    const int* mb = mask + b * SLEN;
    float E[64];
    float C = 0.f;
    float w;

    if (wave == 0) {
      // ---------------- forward: steps 0 .. HALF-1 ----------------
      #pragma unroll
      for (int j = 0; j < 64; ++j) E[j] = __expf(trans[lane * 64 + j]); // row `lane`
      w = (lane == START_TAG) ? 1.f : 0.f;

      float fpre[4]; float mpre[4];
      #pragma unroll
      for (int u = 0; u < 4; ++u) {
        fpre[u] = fb[u * 64 + lane];
        mpre[u] = (float)mb[u];
      }
      for (int s0 = 0; s0 < HALF; s0 += 4) {
        #pragma unroll
        for (int u = 0; u < 4; ++u) {
          float f = __expf(fpre[u]);
          float msk = mpre[u];
          int sn = s0 + 4 + u; sn = (sn < HALF) ? sn : (HALF - 1);
          fpre[u] = fb[sn * 64 + lane];          // prefetch 4 ahead
          mpre[u] = (float)mb[sn];
          float q0 = 0.f, q1 = 0.f, q2 = 0.f, q3 = 0.f;
          #pragma unroll
          for (int j = 0; j < 64; j += 4) {
            q0 = fmaf(E[j + 0], rl(w, j + 0), q0);
            q1 = fmaf(E[j + 1], rl(w, j + 1), q1);
            q2 = fmaf(E[j + 2], rl(w, j + 2), q2);
            q3 = fmaf(E[j + 3], rl(w, j + 3), q3);
          }
          float q = (q0 + q1) + (q2 + q3);
          float wn = q * f;
          float z = rfl(wn);                     // lane0 value: always > 0 (w0==1 invariant)
          float wnn = wn * __builtin_amdgcn_rcpf(z);
          bool mm = (msk != 0.f);
          w = mm ? wnn : w;
          C = mm ? (C + __logf(z)) : C;
        }
      }
    } else {
      // ---------------- backward: steps SLEN-1 .. HALF ----------------
      #pragma unroll
      for (int i = 0; i < 64; ++i) E[i] = __expf(trans[i * 64 + lane]); // column `lane`
      w = __expf(trans[STOP_TAG * 64 + lane]);   // beta init = trans[STOP][:]

      float fpre[4]; float mpre[4];
      #pragma unroll
      for (int u = 0; u < 4; ++u) {
        int s = SLEN - 1 - u;
        fpre[u] = fb[s * 64 + lane];
        mpre[u] = (float)mb[s];
      }
      for (int s0 = 0; s0 < HALF; s0 += 4) {
        #pragma unroll
        for (int u = 0; u < 4; ++u) {
          float f = __expf(fpre[u]);
          float msk = mpre[u];
          int sn = SLEN - 1 - (s0 + 4 + u); sn = (sn >= HALF) ? sn : HALF;
          fpre[u] = fb[sn * 64 + lane];
          mpre[u] = (float)mb[sn];
          float v = w * f;                        // (beta + feat) in linear domain
          float q0 = 0.f, q1 = 0.f, q2 = 0.f, q3 = 0.f;
          #pragma unroll
          for (int i = 0; i < 64; i += 4) {
            q0 = fmaf(E[i + 0], rl(v, i + 0), q0);
            q1 = fmaf(E[i + 1], rl(v, i + 1), q1);
            q2 = fmaf(E[i + 2], rl(v, i + 2), q2);
            q3 = fmaf(E[i + 3], rl(v, i + 3), q3);
          }
          float wn = (q0 + q1) + (q2 + q3);
          float z = rfl(wn);
          float wnn = wn * __builtin_amdgcn_rcpf(z);
          bool mm = (msk != 0.f);
          w = mm ? wnn : w;
          C = mm ? (C + __logf(z)) : C;
        }
      }
    }

    // ---------------- combine alpha_512 · beta_512 ----------------
    if (wave == 1) {
      shf[lane] = w;
      if (lane == 0) shf[64] = C;
    }
    __syncthreads();
    if (wave == 0) {
      shf[66 + lane] = w * shf[lane];
    }
    __syncthreads();
    if (threadIdx.x == 0) {
      float sum = 0.f;
      for (int j = 0; j < 64; ++j) sum += shf[66 + j];
      ws[b] = C + shf[64] + __logf(sum);         // forward_score[b]
    }
  } else {
    // ---------------- gold score ----------------
    const int b = blk - BATCH;
    const int* tb = tags + b * SLEN;
    const int* mb = mask + b * SLEN;
    const float* fb = feats + (size_t)b * SLEN * TAGS;
    float acc = 0.f, cnt = 0.f;
    const int t = threadIdx.x;
    for (int k = 0; k < SLEN / 128; ++k) {
      int s = t + k * 128;
      int cur = tb[s];
      int prev = (s == 0) ? START_TAG : tb[s - 1];
      float m = (float)mb[s];
      acc += m * (fb[s * 64 + cur] + trans[cur * 64 + prev]);
      cnt += m;
    }
    shf[t] = acc;
    shf[128 + t] = cnt;
    __syncthreads();
    if (t == 0) {
      float a = 0.f, c = 0.f;
      for (int i = 0; i < 128; ++i) { a += shf[i]; c += shf[128 + i]; }
      int last_idx = (int)(c + 0.5f);
      int last_tag = (last_idx == 0) ? START_TAG : tb[last_idx - 1];
      ws[BATCH + b] = a + trans[STOP_TAG * 64 + last_tag];
    }
  }
}

__global__ __launch_bounds__(512)
void crf_reduce(const float* __restrict__ ws, float* __restrict__ out) {
  __shared__ float s[512];
  const int t = threadIdx.x;
  s[t] = ws[t] - ws[BATCH + t];   // forward_score[b] - gold_score[b]
  __syncthreads();
  for (int off = 256; off > 0; off >>= 1) {
    if (t < off) s[t] += s[t + off];
    __syncthreads();
  }
  if (t == 0) out[0] = s[0] * (1.f / (float)BATCH);
}

extern "C" void kernel_launch(void* const* d_in, const int* in_sizes, int n_in,
                              void* d_out, int out_size, void* d_ws, size_t ws_size,
                              hipStream_t stream) {
  const float* feats = (const float*)d_in[0];
  const float* trans = (const float*)d_in[1];
  const int* tags = (const int*)d_in[2];
  const int* mask = (const int*)d_in[3];
  float* ws = (float*)d_ws;
  float* out = (float*)d_out;

  crf_main<<<2 * BATCH, 128, 0, stream>>>(feats, trans, tags, mask, ws);
  crf_reduce<<<1, 512, 0, stream>>>(ws, out);
}

// Round 2
// 386.807 us; speedup vs baseline: 1.0637x; 1.0637x over previous
//
#include <hip/hip_runtime.h>

#define TAGS 64
#define START_TAG 62
#define STOP_TAG 63
#define BATCH 512
#define SLEN 1024
#define HALF 512

__device__ __forceinline__ float rl(float v, int l) {
  return __int_as_float(__builtin_amdgcn_readlane(__float_as_int(v), l));
}
__device__ __forceinline__ float rfl(float v) {
  return __int_as_float(__builtin_amdgcn_readfirstlane(__float_as_int(v)));
}
__device__ __forceinline__ int i4_elem(const int4& a, int i) {
  switch (i) { case 0: return a.x; case 1: return a.y; case 2: return a.z; default: return a.w; }
}

// Blocks 0..511: one batch each, wave0 = forward half, wave1 = backward half.
// Blocks 512..1023: gold score for batch (blk-512).
__global__ __launch_bounds__(128, 1)
void crf_main(const float* __restrict__ feats, const float* __restrict__ trans,
              const int* __restrict__ tags, const int* __restrict__ mask,
              float* __restrict__ ws) {
  __shared__ float shf[260];
  const int blk = blockIdx.x;
  const int lane = threadIdx.x & 63;
  const int wave = threadIdx.x >> 6;

  if (blk < BATCH) {
    const int b = blk;
    const float* fb = feats + (size_t)b * SLEN * TAGS;
    const int* mb = mask + b * SLEN;
    float E[64];
    float C = 0.f;
    float w;

    if (wave == 0) {
      // ---------------- forward: steps 0 .. HALF-1 ----------------
      #pragma unroll
      for (int j = 0; j < 64; ++j) E[j] = __expf(trans[lane * 64 + j]); // row `lane`
      w = (lane == START_TAG) ? 1.f : 0.f;

      float fpre[8];
      #pragma unroll
      for (int u = 0; u < 8; ++u) fpre[u] = fb[u * 64 + lane];   // 8-deep prefetch
      int4 mA = *(const int4*)(mb + 0);
      int4 mB = *(const int4*)(mb + 4);

      for (int s0 = 0; s0 < HALF; s0 += 8) {
        int4 mAn = *(const int4*)(mb + s0 + 8);    // mask prefetch, 1 group ahead
        int4 mBn = *(const int4*)(mb + s0 + 12);   // (reads ≤ mb[519]: in-bounds)
        #pragma unroll
        for (int u = 0; u < 8; ++u) {
          float f = __expf(fpre[u]);
          fpre[u] = fb[(s0 + 8 + u) * 64 + lane];  // refill: 8 steps ahead (≤ step 519)
          float q0 = 0.f, q1 = 0.f, q2 = 0.f, q3 = 0.f;
          #pragma unroll
          for (int j = 0; j < 64; j += 4) {
            q0 = fmaf(E[j + 0], rl(w, j + 0), q0);
            q1 = fmaf(E[j + 1], rl(w, j + 1), q1);
            q2 = fmaf(E[j + 2], rl(w, j + 2), q2);
            q3 = fmaf(E[j + 3], rl(w, j + 3), q3);
          }
          float wn = ((q0 + q1) + (q2 + q3)) * f;
          int mm = (u < 4) ? i4_elem(mA, u) : i4_elem(mB, u - 4);
          w = (mm != 0) ? wn : w;
          if (u & 1) {                              // renorm every 2 steps
            float z = rfl(w);                       // w[0] > 0 invariant
            w *= __builtin_amdgcn_rcpf(z);
            C += __logf(z);
          }
        }
        mA = mAn; mB = mBn;
      }
    } else {
      // ---------------- backward: steps SLEN-1 .. HALF ----------------
      #pragma unroll
      for (int i = 0; i < 64; ++i) E[i] = __expf(trans[i * 64 + lane]); // column `lane`
      w = __expf(trans[STOP_TAG * 64 + lane]);   // beta init = trans[STOP][:]

      float fpre[8];
      #pragma unroll
      for (int u = 0; u < 8; ++u) fpre[u] = fb[(SLEN - 1 - u) * 64 + lane];
      int4 mLo = *(const int4*)(mb + 1016);      // s = 1016..1019  (u = 7..4)
      int4 mHi = *(const int4*)(mb + 1020);      // s = 1020..1023  (u = 3..0)

      for (int k0 = 0; k0 < HALF; k0 += 8) {
        int4 mLoN = *(const int4*)(mb + 1008 - k0);
        int4 mHiN = *(const int4*)(mb + 1012 - k0);
        #pragma unroll
        for (int u = 0; u < 8; ++u) {
          float f = __expf(fpre[u]);
          fpre[u] = fb[(SLEN - 1 - (k0 + 8 + u)) * 64 + lane];  // step ≥ 504: in-bounds
          float v = w * f;                        // (beta + feat) in linear domain
          float q0 = 0.f, q1 = 0.f, q2 = 0.f, q3 = 0.f;
          #pragma unroll
          for (int i = 0; i < 64; i += 4) {
            q0 = fmaf(E[i + 0], rl(v, i + 0), q0);
            q1 = fmaf(E[i + 1], rl(v, i + 1), q1);
            q2 = fmaf(E[i + 2], rl(v, i + 2), q2);
            q3 = fmaf(E[i + 3], rl(v, i + 3), q3);
          }
          float wn = (q0 + q1) + (q2 + q3);
          int mm = (u < 4) ? i4_elem(mHi, 3 - u) : i4_elem(mLo, 7 - u);
          w = (mm != 0) ? wn : w;
          if (u & 1) {
            float z = rfl(w);
            w *= __builtin_amdgcn_rcpf(z);
            C += __logf(z);
          }
        }
        mLo = mLoN; mHi = mHiN;
      }
    }

    // ---------------- combine alpha_512 · beta_512 ----------------
    if (wave == 1) {
      shf[lane] = w;
      if (lane == 0) shf[64] = C;
    }
    __syncthreads();
    if (wave == 0) {
      shf[66 + lane] = w * shf[lane];
    }
    __syncthreads();
    if (threadIdx.x == 0) {
      float sum = 0.f;
      for (int j = 0; j < 64; ++j) sum += shf[66 + j];
      ws[b] = C + shf[64] + __logf(sum);         // forward_score[b]
    }
  } else {
    // ---------------- gold score ----------------
    const int b = blk - BATCH;
    const int* tb = tags + b * SLEN;
    const int* mb = mask + b * SLEN;
    const float* fb = feats + (size_t)b * SLEN * TAGS;
    float acc = 0.f, cnt = 0.f;
    const int t = threadIdx.x;
    for (int k = 0; k < SLEN / 128; ++k) {
      int s = t + k * 128;
      int cur = tb[s];
      int prev = (s == 0) ? START_TAG : tb[s - 1];
      float m = (float)mb[s];
      acc += m * (fb[s * 64 + cur] + trans[cur * 64 + prev]);
      cnt += m;
    }
    shf[t] = acc;
    shf[128 + t] = cnt;
    __syncthreads();
    if (t == 0) {
      float a = 0.f, c = 0.f;
      for (int i = 0; i < 128; ++i) { a += shf[i]; c += shf[128 + i]; }
      int last_idx = (int)(c + 0.5f);
      int last_tag = (last_idx == 0) ? START_TAG : tb[last_idx - 1];
      ws[BATCH + b] = a + trans[STOP_TAG * 64 + last_tag];
    }
  }
}

__global__ __launch_bounds__(512)
void crf_reduce(const float* __restrict__ ws, float* __restrict__ out) {
  __shared__ float s[512];
  const int t = threadIdx.x;
  s[t] = ws[t] - ws[BATCH + t];   // forward_score[b] - gold_score[b]
  __syncthreads();
  for (int off = 256; off > 0; off >>= 1) {
    if (t < off) s[t] += s[t + off];
    __syncthreads();
  }
  if (t == 0) out[0] = s[0] * (1.f / (float)BATCH);
}

extern "C" void kernel_launch(void* const* d_in, const int* in_sizes, int n_in,
                              void* d_out, int out_size, void* d_ws, size_t ws_size,
                              hipStream_t stream) {
  const float* feats = (const float*)d_in[0];
  const float* trans = (const float*)d_in[1];
  const int* tags = (const int*)d_in[2];
  const int* mask = (const int*)d_in[3];
  float* ws = (float*)d_ws;
  float* out = (float*)d_out;

  crf_main<<<2 * BATCH, 128, 0, stream>>>(feats, trans, tags, mask, ws);
  crf_reduce<<<1, 512, 0, stream>>>(ws, out);
}

// Round 3
// 374.135 us; speedup vs baseline: 1.0997x; 1.0339x over previous
//
#include <hip/hip_runtime.h>

#define TAGS 64
#define START_TAG 62
#define STOP_TAG 63
#define BATCH 512
#define SLEN 1024
#define HALF 512
#define NGROUP 32   // 512 batches / 16 per wave

typedef float vf4 __attribute__((ext_vector_type(4)));
typedef short short8 __attribute__((ext_vector_type(8)));

// pack two f32 -> bf16x2 by truncation (1 v_perm); bias analyzed ok (~-2 abs on score, thr=105)
__device__ __forceinline__ unsigned pk_bf16(float lo, float hi) {
  return __builtin_amdgcn_perm(__float_as_uint(hi), __float_as_uint(lo), 0x07060302u);
}
__device__ __forceinline__ short bf16_rne(float x) {
  unsigned u = __float_as_uint(x);
  u += 0x7FFFu + ((u >> 16) & 1u);
  return (short)(u >> 16);
}

// Blocks 0..31: chain blocks (wave0 = forward 0..511, wave1 = backward 1023..512), 16 batches each.
// Blocks 32..543: gold score for batch (blk-32).
__global__ __launch_bounds__(128, 1)
void crf_main(const float* __restrict__ feats, const float* __restrict__ trans,
              const int* __restrict__ tags, const int* __restrict__ mask,
              float* __restrict__ ws) {
  __shared__ float shl[64 * 17 + 32];
  const int blk = blockIdx.x;
  const int lane = threadIdx.x & 63;
  const int wave = threadIdx.x >> 6;

  if (blk < NGROUP) {
    const int g = blk;
    const int q = lane >> 4;
    const int col = lane & 15;
    const int b = g * 16 + col;
    const float* fb = feats + (size_t)b * (SLEN * TAGS) + q * 16;
    const int* mb = mask + b * SLEN;

    // ---- A fragments: E (fwd) or E^T (bwd), bf16, custom tag<->slot map ----
    // true_row(t, m=col) = 16*(m>>2) + 4t + (m&3);  true_k(c, kk=q*8+j) = 16q + 8c + j
    short8 A[4][2];
    const int mrow = 16 * (col >> 2) + (col & 3);
    #pragma unroll
    for (int t = 0; t < 4; ++t) {
      #pragma unroll
      for (int c = 0; c < 2; ++c) {
        short8 a;
        #pragma unroll
        for (int j = 0; j < 8; ++j) {
          int R = mrow + 4 * t;
          int K = 16 * q + 8 * c + j;
          float tv = (wave == 0) ? trans[R * 64 + K] : trans[K * 64 + R];
          a[j] = bf16_rne(__expf(tv));
        }
        A[t][c] = a;
      }
    }

    float W[16];   // state in D-layout, slot i <-> true tag 16q + i, col b
    float C = 0.f;

    if (wave == 0) {
      // init: e_START  (true tag 62 -> q=3, slot 14)
      #pragma unroll
      for (int i = 0; i < 16; ++i) W[i] = 0.f;
      if (q == 3) W[14] = 1.f;

      vf4 pf[4][4];
      #pragma unroll
      for (int u = 0; u < 4; ++u)
        #pragma unroll
        for (int v = 0; v < 4; ++v) pf[u][v] = *(const vf4*)(fb + u * 64 + v * 4);
      int4 mc = *(const int4*)(mb);

      for (int k = 0; k < HALF / 4; ++k) {
        int4 mn = (k < HALF / 4 - 1) ? *(const int4*)(mb + 4 * k + 8 - 4) : make_int4(1, 1, 1, 1);
        int allm = mc.x & mc.y & mc.z & mc.w;
        bool fastp = (__ballot(allm != 0) == ~0ull);
        #pragma unroll
        for (int u = 0; u < 4; ++u) {
          union { unsigned uu[4]; short8 s; } B0, B1;
          B0.uu[0] = pk_bf16(W[0], W[1]);   B0.uu[1] = pk_bf16(W[2], W[3]);
          B0.uu[2] = pk_bf16(W[4], W[5]);   B0.uu[3] = pk_bf16(W[6], W[7]);
          B1.uu[0] = pk_bf16(W[8], W[9]);   B1.uu[1] = pk_bf16(W[10], W[11]);
          B1.uu[2] = pk_bf16(W[12], W[13]); B1.uu[3] = pk_bf16(W[14], W[15]);
          vf4 z4 = {0.f, 0.f, 0.f, 0.f};
          vf4 d0 = __builtin_amdgcn_mfma_f32_16x16x32_bf16(A[0][0], B0.s, z4, 0, 0, 0);
          vf4 d1 = __builtin_amdgcn_mfma_f32_16x16x32_bf16(A[1][0], B0.s, z4, 0, 0, 0);
          vf4 d2 = __builtin_amdgcn_mfma_f32_16x16x32_bf16(A[2][0], B0.s, z4, 0, 0, 0);
          vf4 d3 = __builtin_amdgcn_mfma_f32_16x16x32_bf16(A[3][0], B0.s, z4, 0, 0, 0);
          d0 = __builtin_amdgcn_mfma_f32_16x16x32_bf16(A[0][1], B1.s, d0, 0, 0, 0);
          d1 = __builtin_amdgcn_mfma_f32_16x16x32_bf16(A[1][1], B1.s, d1, 0, 0, 0);
          d2 = __builtin_amdgcn_mfma_f32_16x16x32_bf16(A[2][1], B1.s, d2, 0, 0, 0);
          d3 = __builtin_amdgcn_mfma_f32_16x16x32_bf16(A[3][1], B1.s, d3, 0, 0, 0);
          vf4 f0 = pf[u][0], f1 = pf[u][1], f2 = pf[u][2], f3 = pf[u][3];
          int s = 4 * k + u;
          #pragma unroll
          for (int v = 0; v < 4; ++v) pf[u][v] = *(const vf4*)(fb + (s + 4) * 64 + v * 4);
          if (fastp) {
            #pragma unroll
            for (int i = 0; i < 4; ++i) {
              W[i]      = d0[i] * __expf(f0[i]);
              W[4 + i]  = d1[i] * __expf(f1[i]);
              W[8 + i]  = d2[i] * __expf(f2[i]);
              W[12 + i] = d3[i] * __expf(f3[i]);
            }
          } else {
            int mv = (u == 0) ? mc.x : (u == 1) ? mc.y : (u == 2) ? mc.z : mc.w;
            #pragma unroll
            for (int i = 0; i < 4; ++i) {
              W[i]      = mv ? d0[i] * __expf(f0[i]) : W[i];
              W[4 + i]  = mv ? d1[i] * __expf(f1[i]) : W[4 + i];
              W[8 + i]  = mv ? d2[i] * __expf(f2[i]) : W[8 + i];
              W[12 + i] = mv ? d3[i] * __expf(f3[i]) : W[12 + i];
            }
          }
        }
        float z = __shfl(W[0], col);            // true-tag-0 weight of this column; > 0
        float rz = __builtin_amdgcn_rcpf(z);
        C += __logf(z);
        #pragma unroll
        for (int i = 0; i < 16; ++i) W[i] *= rz;
        mc = mn;
      }
    } else {
      // backward: u' = E^T (u .* f_s), s = 1023 .. 512; init u = exp(trans[STOP][:])
      #pragma unroll
      for (int i = 0; i < 16; ++i) W[i] = __expf(trans[STOP_TAG * 64 + (16 * q + i)]);

      vf4 pf[4][4];
      #pragma unroll
      for (int u = 0; u < 4; ++u)
        #pragma unroll
        for (int v = 0; v < 4; ++v) pf[u][v] = *(const vf4*)(fb + (1023 - u) * 64 + v * 4);
      int4 mc = *(const int4*)(mb + 1020);

      for (int k = 0; k < HALF / 4; ++k) {
        int4 mn = (k < HALF / 4 - 1) ? *(const int4*)(mb + 1020 - 4 * (k + 1)) : make_int4(1, 1, 1, 1);
        int allm = mc.x & mc.y & mc.z & mc.w;
        bool fastp = (__ballot(allm != 0) == ~0ull);
        #pragma unroll
        for (int u = 0; u < 4; ++u) {
          vf4 f0 = pf[u][0], f1 = pf[u][1], f2 = pf[u][2], f3 = pf[u][3];
          int s = 1023 - 4 * k - u;
          #pragma unroll
          for (int v = 0; v < 4; ++v) pf[u][v] = *(const vf4*)(fb + (s - 4) * 64 + v * 4);
          float Wt[16];
          #pragma unroll
          for (int i = 0; i < 4; ++i) {
            Wt[i]      = W[i]      * __expf(f0[i]);
            Wt[4 + i]  = W[4 + i]  * __expf(f1[i]);
            Wt[8 + i]  = W[8 + i]  * __expf(f2[i]);
            Wt[12 + i] = W[12 + i] * __expf(f3[i]);
          }
          union { unsigned uu[4]; short8 s8; } B0, B1;
          B0.uu[0] = pk_bf16(Wt[0], Wt[1]);   B0.uu[1] = pk_bf16(Wt[2], Wt[3]);
          B0.uu[2] = pk_bf16(Wt[4], Wt[5]);   B0.uu[3] = pk_bf16(Wt[6], Wt[7]);
          B1.uu[0] = pk_bf16(Wt[8], Wt[9]);   B1.uu[1] = pk_bf16(Wt[10], Wt[11]);
          B1.uu[2] = pk_bf16(Wt[12], Wt[13]); B1.uu[3] = pk_bf16(Wt[14], Wt[15]);
          vf4 z4 = {0.f, 0.f, 0.f, 0.f};
          vf4 d0 = __builtin_amdgcn_mfma_f32_16x16x32_bf16(A[0][0], B0.s8, z4, 0, 0, 0);
          vf4 d1 = __builtin_amdgcn_mfma_f32_16x16x32_bf16(A[1][0], B0.s8, z4, 0, 0, 0);
          vf4 d2 = __builtin_amdgcn_mfma_f32_16x16x32_bf16(A[2][0], B0.s8, z4, 0, 0, 0);
          vf4 d3 = __builtin_amdgcn_mfma_f32_16x16x32_bf16(A[3][0], B0.s8, z4, 0, 0, 0);
          d0 = __builtin_amdgcn_mfma_f32_16x16x32_bf16(A[0][1], B1.s8, d0, 0, 0, 0);
          d1 = __builtin_amdgcn_mfma_f32_16x16x32_bf16(A[1][1], B1.s8, d1, 0, 0, 0);
          d2 = __builtin_amdgcn_mfma_f32_16x16x32_bf16(A[2][1], B1.s8, d2, 0, 0, 0);
          d3 = __builtin_amdgcn_mfma_f32_16x16x32_bf16(A[3][1], B1.s8, d3, 0, 0, 0);
          if (fastp) {
            #pragma unroll
            for (int i = 0; i < 4; ++i) {
              W[i] = d0[i]; W[4 + i] = d1[i]; W[8 + i] = d2[i]; W[12 + i] = d3[i];
            }
          } else {
            int mv = (u == 0) ? mc.w : (u == 1) ? mc.z : (u == 2) ? mc.y : mc.x;
            #pragma unroll
            for (int i = 0; i < 4; ++i) {
              W[i]      = mv ? d0[i] : W[i];
              W[4 + i]  = mv ? d1[i] : W[4 + i];
              W[8 + i]  = mv ? d2[i] : W[8 + i];
              W[12 + i] = mv ? d3[i] : W[12 + i];
            }
          }
        }
        float z = __shfl(W[0], col);
        float rz = __builtin_amdgcn_rcpf(z);
        C += __logf(z);
        #pragma unroll
        for (int i = 0; i < 16; ++i) W[i] *= rz;
        mc = mn;
      }
    }

    // ---- combine: score[b] = Cf + Cb + log( sum_i Wf[i][b] * Wb[i][b] ) ----
    if (wave == 1) {
      #pragma unroll
      for (int i = 0; i < 16; ++i) shl[lane * 17 + i] = W[i];
      shl[lane * 17 + 16] = C;
    }
    __syncthreads();
    if (wave == 0) {
      float p = 0.f;
      #pragma unroll
      for (int i = 0; i < 16; ++i) p += W[i] * shl[lane * 17 + i];
      p += __shfl_xor(p, 16);
      p += __shfl_xor(p, 32);
      float sc = C + shl[lane * 17 + 16] + __logf(p);
      if (lane < 16) ws[b] = sc;
    }
    (void)tags;
  } else {
    // ---------------- gold score (verified in rounds 1-2) ----------------
    const int b = blk - NGROUP;
    const int* tb = tags + b * SLEN;
    const int* mb = mask + b * SLEN;
    const float* fbg = feats + (size_t)b * SLEN * TAGS;
    float acc = 0.f, cnt = 0.f;
    const int t = threadIdx.x;
    for (int k = 0; k < SLEN / 128; ++k) {
      int s = t + k * 128;
      int cur = tb[s];
      int prev = (s == 0) ? START_TAG : tb[s - 1];
      float m = (float)mb[s];
      acc += m * (fbg[s * 64 + cur] + trans[cur * 64 + prev]);
      cnt += m;
    }
    shl[t] = acc;
    shl[128 + t] = cnt;
    __syncthreads();
    if (t == 0) {
      float a = 0.f, c = 0.f;
      for (int i = 0; i < 128; ++i) { a += shl[i]; c += shl[128 + i]; }
      int last_idx = (int)(c + 0.5f);
      int last_tag = (last_idx == 0) ? START_TAG : tb[last_idx - 1];
      ws[BATCH + b] = a + trans[STOP_TAG * 64 + last_tag];
    }
  }
}

__global__ __launch_bounds__(512)
void crf_reduce(const float* __restrict__ ws, float* __restrict__ out) {
  __shared__ float s[512];
  const int t = threadIdx.x;
  s[t] = ws[t] - ws[BATCH + t];
  __syncthreads();
  for (int off = 256; off > 0; off >>= 1) {
    if (t < off) s[t] += s[t + off];
    __syncthreads();
  }
  if (t == 0) out[0] = s[0] * (1.f / (float)BATCH);
}

extern "C" void kernel_launch(void* const* d_in, const int* in_sizes, int n_in,
                              void* d_out, int out_size, void* d_ws, size_t ws_size,
                              hipStream_t stream) {
  const float* feats = (const float*)d_in[0];
  const float* trans = (const float*)d_in[1];
  const int* tags = (const int*)d_in[2];
  const int* mask = (const int*)d_in[3];
  float* ws = (float*)d_ws;
  float* out = (float*)d_out;

  crf_main<<<NGROUP + BATCH, 128, 0, stream>>>(feats, trans, tags, mask, ws);
  crf_reduce<<<1, 512, 0, stream>>>(ws, out);
}

// Round 4
// 309.551 us; speedup vs baseline: 1.3292x; 1.2086x over previous
//
#include <hip/hip_runtime.h>

#define START_TAG 62
#define STOP_TAG 63
#define BATCH 512
#define SLEN 1024
#define NG 32            // batch groups of 16
#define NCHAIN 64        // 32 groups x 2 directions
#define RD 12            // ring depth (slots)
#define AH 8             // async lookahead (steps)
#define SLOTB 4096       // bytes per ring slot: 64 lanes x 64B
#define RINGB (RD * SLOTB)

typedef float vf4 __attribute__((ext_vector_type(4)));
typedef short short8 __attribute__((ext_vector_type(8)));

__device__ __forceinline__ unsigned pk_bf16(float lo, float hi) {
  return __builtin_amdgcn_perm(__float_as_uint(hi), __float_as_uint(lo), 0x07060302u);
}
__device__ __forceinline__ short bf16_rne(float x) {
  unsigned u = __float_as_uint(x);
  u += 0x7FFFu + ((u >> 16) & 1u);
  return (short)(u >> 16);
}
__device__ __forceinline__ vf4 mfma16(short8 a, short8 b, vf4 c) {
  return __builtin_amdgcn_mfma_f32_16x16x32_bf16(a, b, c, 0, 0, 0);
}
// async 16B/lane global->LDS. lds dest = (uniform base) + lane*16 (HW rule).
__device__ __forceinline__ void async16(const void* g, void* l) {
  __builtin_amdgcn_global_load_lds((const __attribute__((address_space(1))) unsigned*)g,
                                   (__attribute__((address_space(3))) unsigned*)l, 16, 0, 0);
}

// One wave advances 16 batches. DIR=0: steps 0..511 (alpha). DIR=1: steps 1023..512 (beta).
// State W[16] per lane: slot i <-> true tag 16q+i, column b = g*16+col (verified R3, absmax 0).
template<int DIR, bool MASKED>
__device__ __forceinline__ void chain_run(const float* __restrict__ feats,
                                          const float* __restrict__ trans,
                                          const int* __restrict__ mask,
                                          float* __restrict__ ws, char* smem, int g) {
  const int lane = threadIdx.x & 63;
  const int q = lane >> 4, col = lane & 15;
  const int b = g * 16 + col;

  // ---- A fragments: E (fwd) / E^T (bwd) in bf16, custom tag<->slot map (R3-verified) ----
  short8 A[4][2];
  const int mrow = 16 * (col >> 2) + (col & 3);
  #pragma unroll
  for (int t = 0; t < 4; ++t) {
    #pragma unroll
    for (int c = 0; c < 2; ++c) {
      short8 a;
      #pragma unroll
      for (int j = 0; j < 8; ++j) {
        int R = mrow + 4 * t, K = 16 * q + 8 * c + j;
        float tv = (DIR == 0) ? trans[R * 64 + K] : trans[K * 64 + R];
        a[j] = bf16_rne(__expf(tv));
      }
      A[t][c] = a;
    }
  }

  float W[16];
  float C = 0.f;
  if (DIR == 0) {
    #pragma unroll
    for (int i = 0; i < 16; ++i) W[i] = 0.f;
    if (q == 3) W[14] = 1.f;                    // true tag 62 = START
  } else {
    #pragma unroll
    for (int i = 0; i < 16; ++i) W[i] = __expf(trans[STOP_TAG * 64 + 16 * q + i]);
  }

  // per-lane global byte base: feats[b][s][q*16 + v*4 ..] = gb + s*256 + v*16
  const char* gb = (const char*)feats + (size_t)b * 262144 + (size_t)q * 64;

  vf4 cur[4];
  int rOff = 0, wOff = 0;
  if constexpr (!MASKED) {
    // drain A-frag/scan loads so manual vmcnt counting owns the queue
    asm volatile("s_waitcnt vmcnt(0)" ::: "memory");
    #pragma unroll
    for (int p = 0; p < AH; ++p) {
      int s = (DIR == 0) ? p : 1023 - p;
      #pragma unroll
      for (int v = 0; v < 4; ++v)
        async16(gb + (size_t)s * 256 + v * 16, smem + p * SLOTB + v * 1024);
    }
    wOff = AH * SLOTB;
    asm volatile("s_waitcnt vmcnt(28)" ::: "memory");  // slot0 resident
    #pragma unroll
    for (int v = 0; v < 4; ++v)
      cur[v] = *(const vf4*)(smem + v * 1024 + lane * 16);
    rOff = SLOTB;
  } else {
    int s0 = (DIR == 0) ? 0 : 1023;
    #pragma unroll
    for (int v = 0; v < 4; ++v)
      cur[v] = *(const vf4*)(gb + (size_t)s0 * 256 + v * 16);
  }

  for (int grp = 0; grp < 128; ++grp) {
    #pragma unroll
    for (int u = 0; u < 4; ++u) {
      const int j = grp * 4 + u;
      float e[16];
      #pragma unroll
      for (int v = 0; v < 4; ++v)
        #pragma unroll
        for (int i = 0; i < 4; ++i) e[v * 4 + i] = __expf(cur[v][i]);

      float P[16];
      #pragma unroll
      for (int i = 0; i < 16; ++i) P[i] = (DIR == 0) ? W[i] : W[i] * e[i];

      union { unsigned uu[4]; short8 s8; } B0, B1;
      B0.uu[0] = pk_bf16(P[0], P[1]);   B0.uu[1] = pk_bf16(P[2], P[3]);
      B0.uu[2] = pk_bf16(P[4], P[5]);   B0.uu[3] = pk_bf16(P[6], P[7]);
      B1.uu[0] = pk_bf16(P[8], P[9]);   B1.uu[1] = pk_bf16(P[10], P[11]);
      B1.uu[2] = pk_bf16(P[12], P[13]); B1.uu[3] = pk_bf16(P[14], P[15]);

      vf4 z4 = {0.f, 0.f, 0.f, 0.f};
      vf4 d0 = mfma16(A[0][0], B0.s8, z4);
      vf4 d1 = mfma16(A[1][0], B0.s8, z4);
      vf4 d2 = mfma16(A[2][0], B0.s8, z4);
      vf4 d3 = mfma16(A[3][0], B0.s8, z4);
      d0 = mfma16(A[0][1], B1.s8, d0);
      d1 = mfma16(A[1][1], B1.s8, d1);
      d2 = mfma16(A[2][1], B1.s8, d2);
      d3 = mfma16(A[3][1], B1.s8, d3);

      int m = 1;
      if constexpr (!MASKED) {
        asm volatile("s_waitcnt vmcnt(24)" ::: "memory");  // slot (j+1) resident
        #pragma unroll
        for (int v = 0; v < 4; ++v)
          cur[v] = *(const vf4*)(smem + rOff + v * 1024 + lane * 16);
        rOff += SLOTB; if (rOff == RINGB) rOff = 0;
        int jp = j + AH; if (jp > 511) jp = 511;           // tail: keep vmcnt uniform
        int sp = (DIR == 0) ? jp : 1023 - jp;
        #pragma unroll
        for (int v = 0; v < 4; ++v)
          async16(gb + (size_t)sp * 256 + v * 16, smem + wOff + v * 1024);
        wOff += SLOTB; if (wOff == RINGB) wOff = 0;
      } else {
        int sj = (DIR == 0) ? j : 1023 - j;
        m = mask[b * 1024 + sj];
        int sn = (DIR == 0) ? (j + 1) : 1023 - (j + 1);    // j=511 -> s=512: in-bounds
        #pragma unroll
        for (int v = 0; v < 4; ++v)
          cur[v] = *(const vf4*)(gb + (size_t)sn * 256 + v * 16);
      }

      #pragma unroll
      for (int i = 0; i < 4; ++i) {
        float n0 = (DIR == 0) ? d0[i] * e[i]      : d0[i];
        float n1 = (DIR == 0) ? d1[i] * e[4 + i]  : d1[i];
        float n2 = (DIR == 0) ? d2[i] * e[8 + i]  : d2[i];
        float n3 = (DIR == 0) ? d3[i] * e[12 + i] : d3[i];
        if (MASKED) {
          W[i]      = m ? n0 : W[i];
          W[4 + i]  = m ? n1 : W[4 + i];
          W[8 + i]  = m ? n2 : W[8 + i];
          W[12 + i] = m ? n3 : W[12 + i];
        } else {
          W[i] = n0; W[4 + i] = n1; W[8 + i] = n2; W[12 + i] = n3;
        }
      }
    }
    // renorm every 4 steps by the column's true-tag-0 weight (invariant transform)
    float z = __shfl(W[0], col);
    float rz = __builtin_amdgcn_rcpf(z);
    C += __logf(z);
    #pragma unroll
    for (int i = 0; i < 16; ++i) W[i] *= rz;
  }

  // epilogue: dump state slab + per-column log-scale
  float* slab = ws + (size_t)(g * 2 + DIR) * 1024;
  #pragma unroll
  for (int t4 = 0; t4 < 4; ++t4) {
    vf4 o = {W[t4 * 4], W[t4 * 4 + 1], W[t4 * 4 + 2], W[t4 * 4 + 3]};
    *(vf4*)(slab + lane * 16 + t4 * 4) = o;
  }
  if (q == 0) ws[65536 + (g * 2 + DIR) * 16 + col] = C;
}

// Blocks 0..63: chains (g=blk>>1, dir=blk&1). Blocks 64..575: gold score for batch blk-64.
__global__ __launch_bounds__(64, 1)
void crf_main(const float* __restrict__ feats, const float* __restrict__ trans,
              const int* __restrict__ tags, const int* __restrict__ mask,
              float* __restrict__ ws) {
  __shared__ char smem[RINGB];
  const int blk = blockIdx.x;
  if (blk < NCHAIN) {
    const int g = blk >> 1, dir = blk & 1;
    const int lane = threadIdx.x & 63;
    const int q = lane >> 4, col = lane & 15;
    const int b = g * 16 + col;
    const int sB = dir ? 512 : 0;
    int anyz = 0;
    for (int it = 0; it < 32; ++it) {
      int4 v = *(const int4*)(mask + b * 1024 + sB + (it * 4 + q) * 4);
      anyz |= (v.x == 0) | (v.y == 0) | (v.z == 0) | (v.w == 0);
    }
    bool allones = (__ballot(anyz != 0) == 0ull);
    if (allones) {
      if (dir == 0) chain_run<0, false>(feats, trans, mask, ws, smem, g);
      else          chain_run<1, false>(feats, trans, mask, ws, smem, g);
    } else {
      if (dir == 0) chain_run<0, true>(feats, trans, mask, ws, smem, g);
      else          chain_run<1, true>(feats, trans, mask, ws, smem, g);
    }
    (void)tags;
  } else {
    const int b = blk - NCHAIN;
    const int* tb = tags + b * SLEN;
    const int* mb = mask + b * SLEN;
    const float* fbg = feats + (size_t)b * 65536;
    float acc = 0.f, cnt = 0.f;
    const int t = threadIdx.x;
    for (int k = 0; k < 16; ++k) {
      int s = t + k * 64;
      int cur = tb[s];
      int prev = (s == 0) ? START_TAG : tb[s - 1];
      float m = (float)mb[s];
      acc += m * (fbg[s * 64 + cur] + trans[cur * 64 + prev]);
      cnt += m;
    }
    #pragma unroll
    for (int o = 1; o < 64; o <<= 1) {
      acc += __shfl_xor(acc, o);
      cnt += __shfl_xor(cnt, o);
    }
    if (t == 0) {
      int last_idx = (int)(cnt + 0.5f);
      int last_tag = (last_idx == 0) ? START_TAG : tb[last_idx - 1];
      ws[66560 + b] = acc + trans[STOP_TAG * 64 + last_tag];
    }
  }
}

__global__ __launch_bounds__(512)
void crf_reduce(const float* __restrict__ ws, float* __restrict__ out) {
  __shared__ float s[512];
  const int t = threadIdx.x;
  const int g = t >> 4, col = t & 15;
  const float* Wf = ws + (size_t)(2 * g) * 1024;
  const float* Wb = ws + (size_t)(2 * g + 1) * 1024;
  float P = 0.f;
  #pragma unroll
  for (int q = 0; q < 4; ++q)
    #pragma unroll
    for (int i = 0; i < 16; ++i)
      P += Wf[(q * 16 + col) * 16 + i] * Wb[(q * 16 + col) * 16 + i];
  float sc = ws[65536 + (2 * g) * 16 + col] + ws[65536 + (2 * g + 1) * 16 + col] + __logf(P);
  s[t] = sc - ws[66560 + t];
  __syncthreads();
  for (int off = 256; off > 0; off >>= 1) {
    if (t < off) s[t] += s[t + off];
    __syncthreads();
  }
  if (t == 0) out[0] = s[0] * (1.f / 512.f);
}

extern "C" void kernel_launch(void* const* d_in, const int* in_sizes, int n_in,
                              void* d_out, int out_size, void* d_ws, size_t ws_size,
                              hipStream_t stream) {
  const float* feats = (const float*)d_in[0];
  const float* trans = (const float*)d_in[1];
  const int* tags = (const int*)d_in[2];
  const int* mask = (const int*)d_in[3];
  float* ws = (float*)d_ws;
  float* out = (float*)d_out;

  crf_main<<<NCHAIN + BATCH, 64, 0, stream>>>(feats, trans, tags, mask, ws);
  crf_reduce<<<1, 512, 0, stream>>>(ws, out);
}

// Round 5
// 301.567 us; speedup vs baseline: 1.3644x; 1.0265x over previous
//
#include <hip/hip_runtime.h>

#define START_TAG 62
#define STOP_TAG 63
#define BATCH 512
#define SLEN 1024
#define NCHAIN 64        // 32 groups x 2 directions
#define RD 16            // ring depth (slots) -> all offsets immediate
#define AH 8             // async lookahead (steps)
#define SLOTB 4096       // bytes per ring slot: 64 lanes x 64B

typedef float vf4 __attribute__((ext_vector_type(4)));
typedef short short8 __attribute__((ext_vector_type(8)));

__device__ __forceinline__ unsigned pk_bf16(float lo, float hi) {
  return __builtin_amdgcn_perm(__float_as_uint(hi), __float_as_uint(lo), 0x07060302u);
}
__device__ __forceinline__ short bf16_rne(float x) {
  unsigned u = __float_as_uint(x);
  u += 0x7FFFu + ((u >> 16) & 1u);
  return (short)(u >> 16);
}
__device__ __forceinline__ vf4 mfma16(short8 a, short8 b, vf4 c) {
  return __builtin_amdgcn_mfma_f32_16x16x32_bf16(a, b, c, 0, 0, 0);
}
__device__ __forceinline__ void async16(const void* g, void* l) {
  __builtin_amdgcn_global_load_lds((const __attribute__((address_space(1))) unsigned*)g,
                                   (__attribute__((address_space(3))) unsigned*)l, 16, 0, 0);
}

// ---- A fragments: E (fwd) / E^T (bwd) in bf16, custom tag<->slot map (R3/R4-verified) ----
template<int DIR>
__device__ __forceinline__ void load_A(const float* __restrict__ trans, short8 A[4][2],
                                       int q, int col) {
  const int mrow = 16 * (col >> 2) + (col & 3);
  #pragma unroll
  for (int t = 0; t < 4; ++t) {
    #pragma unroll
    for (int c = 0; c < 2; ++c) {
      short8 a;
      #pragma unroll
      for (int j = 0; j < 8; ++j) {
        int R = mrow + 4 * t, K = 16 * q + 8 * c + j;
        float tv = (DIR == 0) ? trans[R * 64 + K] : trans[K * 64 + R];
        a[j] = bf16_rne(__expf(tv));
      }
      A[t][c] = a;
    }
  }
}

template<int DIR>
__device__ __forceinline__ void epilogue(float* __restrict__ ws, const float W[16],
                                         float C, int g, int lane, int q, int col) {
  float* slab = ws + (size_t)(g * 2 + DIR) * 1024;
  #pragma unroll
  for (int t4 = 0; t4 < 4; ++t4) {
    vf4 o = {W[t4 * 4], W[t4 * 4 + 1], W[t4 * 4 + 2], W[t4 * 4 + 3]};
    *(vf4*)(slab + lane * 16 + t4 * 4) = o;
  }
  if (q == 0) ws[65536 + (g * 2 + DIR) * 16 + col] = C;
}

// Fast path (mask all ones). One wave advances 16 batches, 512 steps.
template<int DIR>
__device__ __forceinline__ void chain_fast(const float* __restrict__ feats,
                                           const float* __restrict__ trans,
                                           float* __restrict__ ws, char* smem, int g) {
  const int lane = threadIdx.x & 63;
  const int q = lane >> 4, col = lane & 15;
  const int b = g * 16 + col;

  short8 A[4][2];
  load_A<DIR>(trans, A, q, col);

  float W[16];
  if (DIR == 0) {
    #pragma unroll
    for (int i = 0; i < 16; ++i) W[i] = 0.f;
    if (q == 3) W[14] = 1.f;                    // true tag 62 = START
  } else {
    #pragma unroll
    for (int i = 0; i < 16; ++i) W[i] = __expf(trans[STOP_TAG * 64 + 16 * q + i]);
  }

  const char* gb = (const char*)feats + (size_t)b * 262144 + (size_t)q * 64;

  // drain scan/A-frag loads so manual vmcnt counting owns the queue
  asm volatile("s_waitcnt vmcnt(0)" ::: "memory");
  #pragma unroll
  for (int p = 0; p < AH; ++p) {
    size_t s = (DIR == 0) ? (size_t)p : (size_t)(1023 - p);
    #pragma unroll
    for (int v = 0; v < 4; ++v)
      async16(gb + s * 256 + v * 16, smem + p * SLOTB + v * 1024);
  }
  asm volatile("s_waitcnt vmcnt(28)" ::: "memory");  // slot 0 resident
  vf4 cur[4];
  #pragma unroll
  for (int v = 0; v < 4; ++v)
    cur[v] = *(const vf4*)(smem + v * 1024 + lane * 16);

  float C = 0.f, zpend = 1.f;

  for (int bk = 0; bk < 32; ++bk) {
    #pragma unroll
    for (int u = 0; u < 16; ++u) {
      const int j = bk * 16 + u;
      // ---- memory block: prefetch j+AH, wait, read slot j+1 into nxt ----
      int jp = j + AH; if (jp > 511) jp = 511;   // tail: clamped dup, keeps vmcnt uniform
      const size_t sp = (DIR == 0) ? (size_t)jp : (size_t)(1023 - jp);
      const int wslot = (u + AH) & 15;           // compile-time
      #pragma unroll
      for (int v = 0; v < 4; ++v)
        async16(gb + sp * 256 + v * 16, smem + wslot * SLOTB + v * 1024);
      asm volatile("s_waitcnt vmcnt(28)" ::: "memory");  // slot j+1 resident
      const int rslot = (u + 1) & 15;            // compile-time
      vf4 nxt[4];
      #pragma unroll
      for (int v = 0; v < 4; ++v)
        nxt[v] = *(const vf4*)(smem + rslot * SLOTB + v * 1024 + lane * 16);

      // ---- register-only compute for step j, using cur (read one iter ago) ----
      float e[16];
      #pragma unroll
      for (int v = 0; v < 4; ++v)
        #pragma unroll
        for (int i = 0; i < 4; ++i) e[v * 4 + i] = __expf(cur[v][i]);

      float P[16];
      #pragma unroll
      for (int i = 0; i < 16; ++i) P[i] = (DIR == 0) ? W[i] : W[i] * e[i];

      union { unsigned uu[4]; short8 s8; } B0, B1;
      B0.uu[0] = pk_bf16(P[0], P[1]);   B0.uu[1] = pk_bf16(P[2], P[3]);
      B0.uu[2] = pk_bf16(P[4], P[5]);   B0.uu[3] = pk_bf16(P[6], P[7]);
      B1.uu[0] = pk_bf16(P[8], P[9]);   B1.uu[1] = pk_bf16(P[10], P[11]);
      B1.uu[2] = pk_bf16(P[12], P[13]); B1.uu[3] = pk_bf16(P[14], P[15]);

      vf4 z4 = {0.f, 0.f, 0.f, 0.f};
      vf4 d0 = mfma16(A[0][0], B0.s8, z4);
      vf4 d1 = mfma16(A[1][0], B0.s8, z4);
      vf4 d2 = mfma16(A[2][0], B0.s8, z4);
      vf4 d3 = mfma16(A[3][0], B0.s8, z4);
      d0 = mfma16(A[0][1], B1.s8, d0);
      d1 = mfma16(A[1][1], B1.s8, d1);
      d2 = mfma16(A[2][1], B1.s8, d2);
      d3 = mfma16(A[3][1], B1.s8, d3);

      #pragma unroll
      for (int i = 0; i < 4; ++i) {
        W[i]      = (DIR == 0) ? d0[i] * e[i]      : d0[i];
        W[4 + i]  = (DIR == 0) ? d1[i] * e[4 + i]  : d1[i];
        W[8 + i]  = (DIR == 0) ? d2[i] * e[8 + i]  : d2[i];
        W[12 + i] = (DIR == 0) ? d3[i] * e[12 + i] : d3[i];
      }
      #pragma unroll
      for (int v = 0; v < 4; ++v) cur[v] = nxt[v];

      if ((u & 3) == 3) {
        // pipelined renorm: apply z measured 4 steps ago (exact invariant; C logs it),
        // then issue the next measurement — bpermute latency hidden by 4 steps.
        float rz = __builtin_amdgcn_rcpf(zpend);
        C += __logf(zpend);
        #pragma unroll
        for (int i = 0; i < 16; ++i) W[i] *= rz;
        zpend = __shfl(W[0], col);               // true-tag-0 weight of this column (> 0)
      }
    }
  }
  epilogue<DIR>(ws, W, C, g, lane, q, col);
}

// Masked fallback (general mask) — plain loads, per-step mask select (R4-verified).
template<int DIR>
__device__ __forceinline__ void chain_masked(const float* __restrict__ feats,
                                             const float* __restrict__ trans,
                                             const int* __restrict__ mask,
                                             float* __restrict__ ws, int g) {
  const int lane = threadIdx.x & 63;
  const int q = lane >> 4, col = lane & 15;
  const int b = g * 16 + col;

  short8 A[4][2];
  load_A<DIR>(trans, A, q, col);

  float W[16];
  float C = 0.f;
  if (DIR == 0) {
    #pragma unroll
    for (int i = 0; i < 16; ++i) W[i] = 0.f;
    if (q == 3) W[14] = 1.f;
  } else {
    #pragma unroll
    for (int i = 0; i < 16; ++i) W[i] = __expf(trans[STOP_TAG * 64 + 16 * q + i]);
  }

  const char* gb = (const char*)feats + (size_t)b * 262144 + (size_t)q * 64;
  vf4 cur[4];
  {
    size_t s0 = (DIR == 0) ? 0 : 1023;
    #pragma unroll
    for (int v = 0; v < 4; ++v)
      cur[v] = *(const vf4*)(gb + s0 * 256 + (size_t)v * 16);
  }

  for (int grp = 0; grp < 128; ++grp) {
    #pragma unroll
    for (int u = 0; u < 4; ++u) {
      const int j = grp * 4 + u;
      float e[16];
      #pragma unroll
      for (int v = 0; v < 4; ++v)
        #pragma unroll
        for (int i = 0; i < 4; ++i) e[v * 4 + i] = __expf(cur[v][i]);

      float P[16];
      #pragma unroll
      for (int i = 0; i < 16; ++i) P[i] = (DIR == 0) ? W[i] : W[i] * e[i];

      union { unsigned uu[4]; short8 s8; } B0, B1;
      B0.uu[0] = pk_bf16(P[0], P[1]);   B0.uu[1] = pk_bf16(P[2], P[3]);
      B0.uu[2] = pk_bf16(P[4], P[5]);   B0.uu[3] = pk_bf16(P[6], P[7]);
      B1.uu[0] = pk_bf16(P[8], P[9]);   B1.uu[1] = pk_bf16(P[10], P[11]);
      B1.uu[2] = pk_bf16(P[12], P[13]); B1.uu[3] = pk_bf16(P[14], P[15]);

      vf4 z4 = {0.f, 0.f, 0.f, 0.f};
      vf4 d0 = mfma16(A[0][0], B0.s8, z4);
      vf4 d1 = mfma16(A[1][0], B0.s8, z4);
      vf4 d2 = mfma16(A[2][0], B0.s8, z4);
      vf4 d3 = mfma16(A[3][0], B0.s8, z4);
      d0 = mfma16(A[0][1], B1.s8, d0);
      d1 = mfma16(A[1][1], B1.s8, d1);
      d2 = mfma16(A[2][1], B1.s8, d2);
      d3 = mfma16(A[3][1], B1.s8, d3);

      int sj = (DIR == 0) ? j : 1023 - j;
      int m = mask[b * 1024 + sj];
      int sn = (DIR == 0) ? (j + 1) : 1023 - (j + 1);   // j=511 -> s=512: in-bounds
      #pragma unroll
      for (int v = 0; v < 4; ++v)
        cur[v] = *(const vf4*)(gb + (size_t)sn * 256 + (size_t)v * 16);

      #pragma unroll
      for (int i = 0; i < 4; ++i) {
        float n0 = (DIR == 0) ? d0[i] * e[i]      : d0[i];
        float n1 = (DIR == 0) ? d1[i] * e[4 + i]  : d1[i];
        float n2 = (DIR == 0) ? d2[i] * e[8 + i]  : d2[i];
        float n3 = (DIR == 0) ? d3[i] * e[12 + i] : d3[i];
        W[i]      = m ? n0 : W[i];
        W[4 + i]  = m ? n1 : W[4 + i];
        W[8 + i]  = m ? n2 : W[8 + i];
        W[12 + i] = m ? n3 : W[12 + i];
      }
    }
    float z = __shfl(W[0], col);
    float rz = __builtin_amdgcn_rcpf(z);
    C += __logf(z);
    #pragma unroll
    for (int i = 0; i < 16; ++i) W[i] *= rz;
  }
  epilogue<DIR>(ws, W, C, g, lane, q, col);
}

// Blocks 0..63: chains (g=blk>>1, dir=blk&1). Blocks 64..575: gold score for batch blk-64.
__global__ __launch_bounds__(64, 1)
void crf_main(const float* __restrict__ feats, const float* __restrict__ trans,
              const int* __restrict__ tags, const int* __restrict__ mask,
              float* __restrict__ ws) {
  __shared__ char smem[RD * SLOTB];
  const int blk = blockIdx.x;
  if (blk < NCHAIN) {
    const int g = blk >> 1, dir = blk & 1;
    const int lane = threadIdx.x & 63;
    const int q = lane >> 4, col = lane & 15;
    const int b = g * 16 + col;
    const int sB = dir ? 512 : 0;
    int anyz = 0;
    for (int it = 0; it < 32; ++it) {
      int4 v = *(const int4*)(mask + b * 1024 + sB + (it * 4 + q) * 4);
      anyz |= (v.x == 0) | (v.y == 0) | (v.z == 0) | (v.w == 0);
    }
    bool allones = (__ballot(anyz != 0) == 0ull);
    if (allones) {
      if (dir == 0) chain_fast<0>(feats, trans, ws, smem, g);
      else          chain_fast<1>(feats, trans, ws, smem, g);
    } else {
      if (dir == 0) chain_masked<0>(feats, trans, mask, ws, g);
      else          chain_masked<1>(feats, trans, mask, ws, g);
    }
    (void)tags;
  } else {
    const int b = blk - NCHAIN;
    const int* tb = tags + b * SLEN;
    const int* mb = mask + b * SLEN;
    const float* fbg = feats + (size_t)b * 65536;
    float acc = 0.f, cnt = 0.f;
    const int t = threadIdx.x;
    for (int k = 0; k < 16; ++k) {
      int s = t + k * 64;
      int cur = tb[s];
      int prev = (s == 0) ? START_TAG : tb[s - 1];
      float m = (float)mb[s];
      acc += m * (fbg[s * 64 + cur] + trans[cur * 64 + prev]);
      cnt += m;
    }
    #pragma unroll
    for (int o = 1; o < 64; o <<= 1) {
      acc += __shfl_xor(acc, o);
      cnt += __shfl_xor(cnt, o);
    }
    if (t == 0) {
      int last_idx = (int)(cnt + 0.5f);
      int last_tag = (last_idx == 0) ? START_TAG : tb[last_idx - 1];
      ws[66560 + b] = acc + trans[STOP_TAG * 64 + last_tag];
    }
  }
}

__global__ __launch_bounds__(512)
void crf_reduce(const float* __restrict__ ws, float* __restrict__ out) {
  __shared__ float s[512];
  const int t = threadIdx.x;
  const int g = t >> 4, col = t & 15;
  const float* Wf = ws + (size_t)(2 * g) * 1024;
  const float* Wb = ws + (size_t)(2 * g + 1) * 1024;
  float P = 0.f;
  #pragma unroll
  for (int q = 0; q < 4; ++q)
    #pragma unroll
    for (int i = 0; i < 16; ++i)
      P += Wf[(q * 16 + col) * 16 + i] * Wb[(q * 16 + col) * 16 + i];
  float sc = ws[65536 + (2 * g) * 16 + col] + ws[65536 + (2 * g + 1) * 16 + col] + __logf(P);
  s[t] = sc - ws[66560 + t];
  __syncthreads();
  for (int off = 256; off > 0; off >>= 1) {
    if (t < off) s[t] += s[t + off];
    __syncthreads();
  }
  if (t == 0) out[0] = s[0] * (1.f / 512.f);
}

extern "C" void kernel_launch(void* const* d_in, const int* in_sizes, int n_in,
                              void* d_out, int out_size, void* d_ws, size_t ws_size,
                              hipStream_t stream) {
  const float* feats = (const float*)d_in[0];
  const float* trans = (const float*)d_in[1];
  const int* tags = (const int*)d_in[2];
  const int* mask = (const int*)d_in[3];
  float* ws = (float*)d_ws;
  float* out = (float*)d_out;

  crf_main<<<NCHAIN + BATCH, 64, 0, stream>>>(feats, trans, tags, mask, ws);
  crf_reduce<<<1, 512, 0, stream>>>(ws, out);
}

// Round 6
// 299.398 us; speedup vs baseline: 1.3742x; 1.0072x over previous
//
#include <hip/hip_runtime.h>

#define START_TAG 62
#define STOP_TAG 63
#define BATCH 512
#define SLEN 1024
#define NCHAIN 64        // 32 groups x 2 directions

typedef float vf4 __attribute__((ext_vector_type(4)));
typedef short short8 __attribute__((ext_vector_type(8)));

__device__ __forceinline__ unsigned pk_bf16(float lo, float hi) {
  return __builtin_amdgcn_perm(__float_as_uint(hi), __float_as_uint(lo), 0x07060302u);
}
__device__ __forceinline__ short bf16_rne(float x) {
  unsigned u = __float_as_uint(x);
  u += 0x7FFFu + ((u >> 16) & 1u);
  return (short)(u >> 16);
}
__device__ __forceinline__ vf4 mfma16(short8 a, short8 b, vf4 c) {
  return __builtin_amdgcn_mfma_f32_16x16x32_bf16(a, b, c, 0, 0, 0);
}

// 64B load (4x dwordx4) via asm so the compiler's waitcnt pass cannot see it:
// no compiler-inserted vmcnt drains, loads stay where issued.
#define FIFO_LOAD(slot, addr)                                              \
  asm volatile("global_load_dwordx4 %0, %4, off\n\t"                       \
               "global_load_dwordx4 %1, %4, off offset:16\n\t"             \
               "global_load_dwordx4 %2, %4, off offset:32\n\t"             \
               "global_load_dwordx4 %3, %4, off offset:48"                 \
               : "=v"(F[slot][0]), "=v"(F[slot][1]),                       \
                 "=v"(F[slot][2]), "=v"(F[slot][3])                        \
               : "v"(addr) : "memory")

// wait until the oldest 4 loads (the slot we are about to read) have landed;
// "+v" ties create the data dependence so consumers can't be hoisted above.
#define FIFO_WAIT12(slot)                                                  \
  asm volatile("s_waitcnt vmcnt(12)"                                       \
               : "+v"(F[slot][0]), "+v"(F[slot][1]),                       \
                 "+v"(F[slot][2]), "+v"(F[slot][3]) :: "memory")

// ---- A fragments: E (fwd) / E^T (bwd) in bf16, custom tag<->slot map (R3/R4-verified) ----
template<int DIR>
__device__ __forceinline__ void load_A(const float* __restrict__ trans, short8 A[4][2],
                                       int q, int col) {
  const int mrow = 16 * (col >> 2) + (col & 3);
  #pragma unroll
  for (int t = 0; t < 4; ++t) {
    #pragma unroll
    for (int c = 0; c < 2; ++c) {
      short8 a;
      #pragma unroll
      for (int j = 0; j < 8; ++j) {
        int R = mrow + 4 * t, K = 16 * q + 8 * c + j;
        float tv = (DIR == 0) ? trans[R * 64 + K] : trans[K * 64 + R];
        a[j] = bf16_rne(__expf(tv));
      }
      A[t][c] = a;
    }
  }
}

template<int DIR>
__device__ __forceinline__ void epilogue(float* __restrict__ ws, const float W[16],
                                         float C, int g, int lane, int q, int col) {
  float* slab = ws + (size_t)(g * 2 + DIR) * 1024;
  #pragma unroll
  for (int t4 = 0; t4 < 4; ++t4) {
    vf4 o = {W[t4 * 4], W[t4 * 4 + 1], W[t4 * 4 + 2], W[t4 * 4 + 3]};
    *(vf4*)(slab + lane * 16 + t4 * 4) = o;
  }
  if (q == 0) ws[65536 + (g * 2 + DIR) * 16 + col] = C;
}

// Fast path (mask all ones). One wave advances 16 batches, 512 steps.
// Register FIFO depth 4 (64 VGPRs), occupancy is 1 wave/CU by design so VGPRs are free.
template<int DIR>
__device__ __forceinline__ void chain_fast(const float* __restrict__ feats,
                                           const float* __restrict__ trans,
                                           float* __restrict__ ws, int g) {
  const int lane = threadIdx.x & 63;
  const int q = lane >> 4, col = lane & 15;
  const int b = g * 16 + col;

  short8 A[4][2];
  load_A<DIR>(trans, A, q, col);

  float W[16];
  if (DIR == 0) {
    #pragma unroll
    for (int i = 0; i < 16; ++i) W[i] = 0.f;
    if (q == 3) W[14] = 1.f;                    // true tag 62 = START
  } else {
    #pragma unroll
    for (int i = 0; i < 16; ++i) W[i] = __expf(trans[STOP_TAG * 64 + 16 * q + i]);
  }

  const char* gb = (const char*)feats + (size_t)b * 262144 + (size_t)q * 64;
  const ptrdiff_t delta = (DIR == 0) ? 256 : -256;

  vf4 F[4][4];
  // drain compiler-tracked loads so our manual vmcnt counting owns the queue
  asm volatile("s_waitcnt vmcnt(0)" ::: "memory");
  #pragma unroll
  for (int p = 0; p < 4; ++p) {
    const char* a = gb + (size_t)((DIR == 0) ? p : 1023 - p) * 256;
    FIFO_LOAD(p, a);
  }
  const char* ap = gb + (size_t)((DIR == 0) ? 4 : 1019) * 256;  // next load: step 4

  float C = 0.f, zpend = 1.f;

  for (int bk = 0; bk < 32; ++bk) {
    #pragma unroll
    for (int u = 0; u < 16; ++u) {
      const int sl = u & 3;                     // (bk*16+u) % 4, compile-time
      FIFO_WAIT12(sl);                          // slot for step j resident

      float e[16];
      #pragma unroll
      for (int v = 0; v < 4; ++v)
        #pragma unroll
        for (int i = 0; i < 4; ++i) e[v * 4 + i] = __expf(F[sl][v][i]);

      // reissue slot for step j+4 (address always in-bounds: step<=515 of this batch)
      FIFO_LOAD(sl, ap);
      ap += delta;

      float P[16];
      #pragma unroll
      for (int i = 0; i < 16; ++i) P[i] = (DIR == 0) ? W[i] : W[i] * e[i];

      union { unsigned uu[4]; short8 s8; } B0, B1;
      B0.uu[0] = pk_bf16(P[0], P[1]);   B0.uu[1] = pk_bf16(P[2], P[3]);
      B0.uu[2] = pk_bf16(P[4], P[5]);   B0.uu[3] = pk_bf16(P[6], P[7]);
      B1.uu[0] = pk_bf16(P[8], P[9]);   B1.uu[1] = pk_bf16(P[10], P[11]);
      B1.uu[2] = pk_bf16(P[12], P[13]); B1.uu[3] = pk_bf16(P[14], P[15]);

      vf4 z4 = {0.f, 0.f, 0.f, 0.f};
      vf4 d0 = mfma16(A[0][0], B0.s8, z4);
      vf4 d1 = mfma16(A[1][0], B0.s8, z4);
      vf4 d2 = mfma16(A[2][0], B0.s8, z4);
      vf4 d3 = mfma16(A[3][0], B0.s8, z4);
      d0 = mfma16(A[0][1], B1.s8, d0);
      d1 = mfma16(A[1][1], B1.s8, d1);
      d2 = mfma16(A[2][1], B1.s8, d2);
      d3 = mfma16(A[3][1], B1.s8, d3);

      #pragma unroll
      for (int i = 0; i < 4; ++i) {
        W[i]      = (DIR == 0) ? d0[i] * e[i]      : d0[i];
        W[4 + i]  = (DIR == 0) ? d1[i] * e[4 + i]  : d1[i];
        W[8 + i]  = (DIR == 0) ? d2[i] * e[8 + i]  : d2[i];
        W[12 + i] = (DIR == 0) ? d3[i] * e[12 + i] : d3[i];
      }

      if ((u & 3) == 3) {
        // pipelined renorm (R5-verified): apply z measured 4 steps ago, issue next probe
        float rz = __builtin_amdgcn_rcpf(zpend);
        C += __logf(zpend);
        #pragma unroll
        for (int i = 0; i < 16; ++i) W[i] *= rz;
        zpend = __shfl(W[0], col);               // true-tag-0 weight of this column (> 0)
      }
    }
  }

  // drain in-flight FIFO loads with all slots tied: no dead-def register reuse hazard
  asm volatile("s_waitcnt vmcnt(0)"
               : "+v"(F[0][0]), "+v"(F[0][1]), "+v"(F[0][2]), "+v"(F[0][3]),
                 "+v"(F[1][0]), "+v"(F[1][1]), "+v"(F[1][2]), "+v"(F[1][3]),
                 "+v"(F[2][0]), "+v"(F[2][1]), "+v"(F[2][2]), "+v"(F[2][3]),
                 "+v"(F[3][0]), "+v"(F[3][1]), "+v"(F[3][2]), "+v"(F[3][3]) :: "memory");

  epilogue<DIR>(ws, W, C, g, lane, q, col);
}

// Masked fallback (general mask) — plain loads, per-step mask select (R4-verified).
template<int DIR>
__device__ __forceinline__ void chain_masked(const float* __restrict__ feats,
                                             const float* __restrict__ trans,
                                             const int* __restrict__ mask,
                                             float* __restrict__ ws, int g) {
  const int lane = threadIdx.x & 63;
  const int q = lane >> 4, col = lane & 15;
  const int b = g * 16 + col;

  short8 A[4][2];
  load_A<DIR>(trans, A, q, col);

  float W[16];
  float C = 0.f;
  if (DIR == 0) {
    #pragma unroll
    for (int i = 0; i < 16; ++i) W[i] = 0.f;
    if (q == 3) W[14] = 1.f;
  } else {
    #pragma unroll
    for (int i = 0; i < 16; ++i) W[i] = __expf(trans[STOP_TAG * 64 + 16 * q + i]);
  }

  const char* gb = (const char*)feats + (size_t)b * 262144 + (size_t)q * 64;
  vf4 cur[4];
  {
    size_t s0 = (DIR == 0) ? 0 : 1023;
    #pragma unroll
    for (int v = 0; v < 4; ++v)
      cur[v] = *(const vf4*)(gb + s0 * 256 + (size_t)v * 16);
  }

  for (int grp = 0; grp < 128; ++grp) {
    #pragma unroll
    for (int u = 0; u < 4; ++u) {
      const int j = grp * 4 + u;
      float e[16];
      #pragma unroll
      for (int v = 0; v < 4; ++v)
        #pragma unroll
        for (int i = 0; i < 4; ++i) e[v * 4 + i] = __expf(cur[v][i]);

      float P[16];
      #pragma unroll
      for (int i = 0; i < 16; ++i) P[i] = (DIR == 0) ? W[i] : W[i] * e[i];

      union { unsigned uu[4]; short8 s8; } B0, B1;
      B0.uu[0] = pk_bf16(P[0], P[1]);   B0.uu[1] = pk_bf16(P[2], P[3]);
      B0.uu[2] = pk_bf16(P[4], P[5]);   B0.uu[3] = pk_bf16(P[6], P[7]);
      B1.uu[0] = pk_bf16(P[8], P[9]);   B1.uu[1] = pk_bf16(P[10], P[11]);
      B1.uu[2] = pk_bf16(P[12], P[13]); B1.uu[3] = pk_bf16(P[14], P[15]);

      vf4 z4 = {0.f, 0.f, 0.f, 0.f};
      vf4 d0 = mfma16(A[0][0], B0.s8, z4);
      vf4 d1 = mfma16(A[1][0], B0.s8, z4);
      vf4 d2 = mfma16(A[2][0], B0.s8, z4);
      vf4 d3 = mfma16(A[3][0], B0.s8, z4);
      d0 = mfma16(A[0][1], B1.s8, d0);
      d1 = mfma16(A[1][1], B1.s8, d1);
      d2 = mfma16(A[2][1], B1.s8, d2);
      d3 = mfma16(A[3][1], B1.s8, d3);

      int sj = (DIR == 0) ? j : 1023 - j;
      int m = mask[b * 1024 + sj];
      int sn = (DIR == 0) ? (j + 1) : 1023 - (j + 1);   // j=511 -> s=512: in-bounds
      #pragma unroll
      for (int v = 0; v < 4; ++v)
        cur[v] = *(const vf4*)(gb + (size_t)sn * 256 + (size_t)v * 16);

      #pragma unroll
      for (int i = 0; i < 4; ++i) {
        float n0 = (DIR == 0) ? d0[i] * e[i]      : d0[i];
        float n1 = (DIR == 0) ? d1[i] * e[4 + i]  : d1[i];
        float n2 = (DIR == 0) ? d2[i] * e[8 + i]  : d2[i];
        float n3 = (DIR == 0) ? d3[i] * e[12 + i] : d3[i];
        W[i]      = m ? n0 : W[i];
        W[4 + i]  = m ? n1 : W[4 + i];
        W[8 + i]  = m ? n2 : W[8 + i];
        W[12 + i] = m ? n3 : W[12 + i];
      }
    }
    float z = __shfl(W[0], col);
    float rz = __builtin_amdgcn_rcpf(z);
    C += __logf(z);
    #pragma unroll
    for (int i = 0; i < 16; ++i) W[i] *= rz;
  }
  epilogue<DIR>(ws, W, C, g, lane, q, col);
}

// Blocks 0..63: chains (g=blk>>1, dir=blk&1). Blocks 64..575: gold score for batch blk-64.
__global__ __launch_bounds__(64, 1)
void crf_main(const float* __restrict__ feats, const float* __restrict__ trans,
              const int* __restrict__ tags, const int* __restrict__ mask,
              float* __restrict__ ws) {
  const int blk = blockIdx.x;
  if (blk < NCHAIN) {
    const int g = blk >> 1, dir = blk & 1;
    const int lane = threadIdx.x & 63;
    const int q = lane >> 4, col = lane & 15;
    const int b = g * 16 + col;
    const int sB = dir ? 512 : 0;
    int anyz = 0;
    for (int it = 0; it < 32; ++it) {
      int4 v = *(const int4*)(mask + b * 1024 + sB + (it * 4 + q) * 4);
      anyz |= (v.x == 0) | (v.y == 0) | (v.z == 0) | (v.w == 0);
    }
    bool allones = (__ballot(anyz != 0) == 0ull);
    if (allones) {
      if (dir == 0) chain_fast<0>(feats, trans, ws, g);
      else          chain_fast<1>(feats, trans, ws, g);
    } else {
      if (dir == 0) chain_masked<0>(feats, trans, mask, ws, g);
      else          chain_masked<1>(feats, trans, mask, ws, g);
    }
    (void)tags;
  } else {
    const int b = blk - NCHAIN;
    const int* tb = tags + b * SLEN;
    const int* mb = mask + b * SLEN;
    const float* fbg = feats + (size_t)b * 65536;
    float acc = 0.f, cnt = 0.f;
    const int t = threadIdx.x;
    for (int k = 0; k < 16; ++k) {
      int s = t + k * 64;
      int cur = tb[s];
      int prev = (s == 0) ? START_TAG : tb[s - 1];
      float m = (float)mb[s];
      acc += m * (fbg[s * 64 + cur] + trans[cur * 64 + prev]);
      cnt += m;
    }
    #pragma unroll
    for (int o = 1; o < 64; o <<= 1) {
      acc += __shfl_xor(acc, o);
      cnt += __shfl_xor(cnt, o);
    }
    if (t == 0) {
      int last_idx = (int)(cnt + 0.5f);
      int last_tag = (last_idx == 0) ? START_TAG : tb[last_idx - 1];
      ws[66560 + b] = acc + trans[STOP_TAG * 64 + last_tag];
    }
  }
}

__global__ __launch_bounds__(512)
void crf_reduce(const float* __restrict__ ws, float* __restrict__ out) {
  __shared__ float s[512];
  const int t = threadIdx.x;
  const int g = t >> 4, col = t & 15;
  const float* Wf = ws + (size_t)(2 * g) * 1024;
  const float* Wb = ws + (size_t)(2 * g + 1) * 1024;
  float P = 0.f;
  #pragma unroll
  for (int q = 0; q < 4; ++q)
    #pragma unroll
    for (int i = 0; i < 16; ++i)
      P += Wf[(q * 16 + col) * 16 + i] * Wb[(q * 16 + col) * 16 + i];
  float sc = ws[65536 + (2 * g) * 16 + col] + ws[65536 + (2 * g + 1) * 16 + col] + __logf(P);
  s[t] = sc - ws[66560 + t];
  __syncthreads();
  for (int off = 256; off > 0; off >>= 1) {
    if (t < off) s[t] += s[t + off];
    __syncthreads();
  }
  if (t == 0) out[0] = s[0] * (1.f / 512.f);
}

extern "C" void kernel_launch(void* const* d_in, const int* in_sizes, int n_in,
                              void* d_out, int out_size, void* d_ws, size_t ws_size,
                              hipStream_t stream) {
  const float* feats = (const float*)d_in[0];
  const float* trans = (const float*)d_in[1];
  const int* tags = (const int*)d_in[2];
  const int* mask = (const int*)d_in[3];
  float* ws = (float*)d_ws;
  float* out = (float*)d_out;

  crf_main<<<NCHAIN + BATCH, 64, 0, stream>>>(feats, trans, tags, mask, ws);
  crf_reduce<<<1, 512, 0, stream>>>(ws, out);
}